// Round 3
// baseline (193.607 us; speedup 1.0000x reference)
//
#include <hip/hip_runtime.h>
#include <math.h>

#define BB 2
#define NN 1024
#define DD 48
#define DH 12
#define BI 16
#define BJ 16
#define PSTR 49   // padded pos-tile row stride

__device__ __forceinline__ float gelu_exact(float x) {
    return 0.5f * x * (1.0f + erff(x * 0.70710678118654752f));
}
// tanh-form GELU: max abs deviation from exact ~2e-3; outputs damped by dt=0.1
__device__ __forceinline__ float gelu_fast(float x) {
    float u = x * x;
    float p = __builtin_fmaf(0.044715f * x, u, x);     // x + 0.044715 x^3
    float z = 1.5957691216057308f * p;                 // 2*sqrt(2/pi)*p
    float e = __expf(-z);                              // v_exp_f32 path
    return x * __builtin_amdgcn_rcpf(1.0f + e);        // x * sigmoid(z)
}
__device__ __forceinline__ float softplus_f(float x) {
    return (x > 20.0f) ? x : log1pf(expf(x));
}

// ---------------- mass MLP + force accumulator zeroing ----------------
__global__ void mass_kernel(const float* __restrict__ pos,
                            const float* __restrict__ m_w1, const float* __restrict__ m_b1,
                            const float* __restrict__ m_w2, const float* __restrict__ m_b2,
                            float* __restrict__ mass_out, float* __restrict__ force_acc) {
    int p = blockIdx.x * blockDim.x + threadIdx.x;
    if (p >= BB * NN) return;

    float* fr = force_acc + (size_t)p * DD;
    #pragma unroll
    for (int d = 0; d < DD; ++d) fr[d] = 0.0f;

    const float* pp = pos + p * DD;
    float x[DD];
    #pragma unroll
    for (int d = 0; d < DD; ++d) x[d] = pp[d];
    float m2 = m_b2[0];
    #pragma unroll
    for (int k = 0; k < DH; ++k) {
        float h = m_b1[k];
        #pragma unroll
        for (int d = 0; d < DD; ++d) h += x[d] * m_w1[d * DH + k];
        m2 += gelu_exact(h) * m_w2[k];
    }
    mass_out[p] = softplus_f(m2);
}

// ---------------- pairwise force ----------------
__global__ __launch_bounds__(256) void force_kernel(
    const float* __restrict__ pos,
    const float* __restrict__ f_w1, const float* __restrict__ f_b1,
    const float* __restrict__ f_w2, const float* __restrict__ f_b2,
    const float* __restrict__ f_w3, const float* __restrict__ f_b3,
    const float* __restrict__ mass, float* __restrict__ force_acc) {
    __shared__ float sPi[BI * PSTR];
    __shared__ float sPj[BJ * PSTR];
    __shared__ float sW2T[DD * DD];   // sW2T[k*48+c] = w2[c][k]
    __shared__ float sW1[3 * DD];
    __shared__ float sB1[DD];
    __shared__ float sB2[DD];
    __shared__ float sW3[DD];
    __shared__ float sMi[BI], sMj[BJ];
    __shared__ float sRat[BI][BJ + 1];

    const int tpb = NN / BI;              // 64
    const int TP = tpb * (tpb + 1) / 2;   // 2080
    int bid = blockIdx.x;
    int b = bid / TP;
    int tp = bid - b * TP;
    int it = (int)((sqrtf(8.0f * (float)tp + 1.0f) - 1.0f) * 0.5f);
    while ((it + 1) * (it + 2) / 2 <= tp) ++it;
    while (it * (it + 1) / 2 > tp) --it;
    int jt = tp - it * (it + 1) / 2;

    int i0 = it * BI, j0 = jt * BJ;
    int tid = threadIdx.x;

    for (int e = tid; e < DD * DD; e += 256) {
        int c = e / DD, k = e - c * DD;
        sW2T[k * DD + c] = f_w2[e];
    }
    if (tid < 3 * DD) sW1[tid] = f_w1[tid];
    if (tid < DD) { sB1[tid] = f_b1[tid]; sB2[tid] = f_b2[tid]; sW3[tid] = f_w3[tid]; }
    for (int e = tid; e < BI * DD; e += 256) {
        int r = e / DD, d = e - r * DD;
        sPi[r * PSTR + d] = pos[(b * NN + i0 + r) * DD + d];
        sPj[r * PSTR + d] = pos[(b * NN + j0 + r) * DD + d];
    }
    if (tid < BI) sMi[tid] = mass[b * NN + i0 + tid];
    else if (tid < BI + BJ) sMj[tid - BI] = mass[b * NN + j0 + (tid - BI)];
    __syncthreads();

    // ---- Phase A: one thread per (i,j) pair ----
    int ti = tid >> 4, tj = tid & 15;
    int gi = i0 + ti, gj = j0 + tj;
    const float* pi = &sPi[ti * PSTR];
    const float* pj = &sPj[tj * PSTR];

    float s2 = 0.0f;
    #pragma unroll
    for (int d = 0; d < DD; ++d) { float df = pi[d] - pj[d]; s2 += df * df; }
    float dist = fmaxf(sqrtf(s2), 0.01f);

    float mi = sMi[ti], mj = sMj[tj];
    // FULL unroll: all h1 indices compile-time -> h1 stays in VGPRs (no scratch)
    float h1[DD];
    #pragma unroll
    for (int k = 0; k < DD; ++k) {
        float t = sB1[k] + dist * sW1[k] + mi * sW1[DD + k] + mj * sW1[2 * DD + k];
        h1[k] = gelu_fast(t);
    }
    float fm = f_b3[0];
    #pragma unroll
    for (int k = 0; k < DD; ++k) {
        float t = sB2[k];
        const float* wr = &sW2T[k * DD];
        #pragma unroll
        for (int c = 0; c < DD; ++c) t += h1[c] * wr[c];
        fm += gelu_fast(t) * sW3[k];
    }
    float ratio = (gj <= gi) ? (fm / dist) : 0.0f;  // j==i: disp=0 -> contributes 0
    sRat[ti][tj] = ratio;
    __syncthreads();

    // ---- Phase B: thread=(i, d-group of 3) accumulates over j ----
    int ti2 = tid >> 4, dg = tid & 15;
    int d0 = dg * 3;
    const float* pi2 = &sPi[ti2 * PSTR];
    float f0 = 0.0f, f1 = 0.0f, f2 = 0.0f;
    #pragma unroll
    for (int t = 0; t < BJ; ++t) {
        float r = sRat[ti2][t];
        const float* pj2 = &sPj[t * PSTR];
        f0 += r * (pi2[d0 + 0] - pj2[d0 + 0]);
        f1 += r * (pi2[d0 + 1] - pj2[d0 + 1]);
        f2 += r * (pi2[d0 + 2] - pj2[d0 + 2]);
    }
    float* fdst = force_acc + ((size_t)(b * NN + i0 + ti2) * DD + d0);
    atomicAdd(fdst + 0, f0);
    atomicAdd(fdst + 1, f1);
    atomicAdd(fdst + 2, f2);
}

// ---------------- integrate ----------------
__global__ void integrate_kernel(const float* __restrict__ pos, const float* __restrict__ vel,
                                 const float* __restrict__ force, const float* __restrict__ mass,
                                 const float* __restrict__ damping_p, const float* __restrict__ dt_p,
                                 float* __restrict__ out) {
    int e = blockIdx.x * blockDim.x + threadIdx.x;
    if (e >= BB * NN * DD) return;
    int p = e / DD;
    float damping = damping_p[0], dt = dt_p[0];
    float acc = force[e] / (mass[p] + 0.1f);
    float nv = damping * vel[e] + dt * acc;
    float np = pos[e] + dt * nv;
    out[e] = np;
    out[BB * NN * DD + e] = nv;
}

extern "C" void kernel_launch(void* const* d_in, const int* in_sizes, int n_in,
                              void* d_out, int out_size, void* d_ws, size_t ws_size,
                              hipStream_t stream) {
    const float* pos  = (const float*)d_in[0];
    const float* vel  = (const float*)d_in[1];
    const float* m_w1 = (const float*)d_in[2];
    const float* m_b1 = (const float*)d_in[3];
    const float* m_w2 = (const float*)d_in[4];
    const float* m_b2 = (const float*)d_in[5];
    const float* f_w1 = (const float*)d_in[6];
    const float* f_b1 = (const float*)d_in[7];
    const float* f_w2 = (const float*)d_in[8];
    const float* f_b2 = (const float*)d_in[9];
    const float* f_w3 = (const float*)d_in[10];
    const float* f_b3 = (const float*)d_in[11];
    const float* damping = (const float*)d_in[12];
    const float* dt   = (const float*)d_in[13];

    float* force_ws = (float*)d_ws;                 // BB*NN*DD floats
    float* mass_ws  = force_ws + BB * NN * DD;      // BB*NN floats

    mass_kernel<<<(BB * NN + 255) / 256, 256, 0, stream>>>(pos, m_w1, m_b1, m_w2, m_b2,
                                                           mass_ws, force_ws);

    const int tpb = NN / BI;
    const int TP = tpb * (tpb + 1) / 2;
    force_kernel<<<BB * TP, 256, 0, stream>>>(pos, f_w1, f_b1, f_w2, f_b2, f_w3, f_b3,
                                              mass_ws, force_ws);

    integrate_kernel<<<(BB * NN * DD + 255) / 256, 256, 0, stream>>>(
        pos, vel, force_ws, mass_ws, damping, dt, (float*)d_out);
}

// Round 4
// 76.776 us; speedup vs baseline: 2.5217x; 2.5217x over previous
//
#include <hip/hip_runtime.h>
#include <math.h>

#define BB 2
#define NN 1024
#define DD 48
#define DH 12
#define BI 16
#define BJ 16
#define PSTR 52   // padded pos row stride (floats): 208B, 16B-aligned, <=2-way bank alias

// force_mag(dist, mi, mj) lookup table
#define ND 128
#define NM 16
#define D_LO 1.0f
#define D_HI 20.0f
#define M_LO 0.0f
#define M_HI 2.0f
#define DSTEP ((D_HI - D_LO) / (float)(ND - 1))
#define DINV  ((float)(ND - 1) / (D_HI - D_LO))
#define MSTEP ((M_HI - M_LO) / (float)(NM - 1))
#define MINV  ((float)(NM - 1) / (M_HI - M_LO))

__device__ __forceinline__ float gelu_exact(float x) {
    return 0.5f * x * (1.0f + erff(x * 0.70710678118654752f));
}
__device__ __forceinline__ float softplus_f(float x) {
    return (x > 20.0f) ? x : log1pf(expf(x));
}

// ---------------- mass MLP + force accumulator zeroing ----------------
__global__ void mass_kernel(const float* __restrict__ pos,
                            const float* __restrict__ m_w1, const float* __restrict__ m_b1,
                            const float* __restrict__ m_w2, const float* __restrict__ m_b2,
                            float* __restrict__ mass_out, float* __restrict__ force_acc) {
    int p = blockIdx.x * blockDim.x + threadIdx.x;
    if (p >= BB * NN) return;

    float* fr = force_acc + (size_t)p * DD;
    #pragma unroll
    for (int d = 0; d < DD; ++d) fr[d] = 0.0f;

    const float* pp = pos + p * DD;
    float x[DD];
    #pragma unroll
    for (int d = 0; d < DD; ++d) x[d] = pp[d];
    float m2 = m_b2[0];
    #pragma unroll
    for (int k = 0; k < DH; ++k) {
        float h = m_b1[k];
        #pragma unroll
        for (int d = 0; d < DD; ++d) h += x[d] * m_w1[d * DH + k];
        m2 += gelu_exact(h) * m_w2[k];
    }
    mass_out[p] = softplus_f(m2);
}

// ---------------- force-magnitude table build (exact erf GELU) ----------------
// table[(di*NM + mi)*NM + mj] = force_net(dist(di), m(mi), m(mj))
__global__ __launch_bounds__(256) void table_kernel(
    const float* __restrict__ f_w1, const float* __restrict__ f_b1,
    const float* __restrict__ f_w2, const float* __restrict__ f_b2,
    const float* __restrict__ f_w3, const float* __restrict__ f_b3,
    float* __restrict__ table) {
    __shared__ float sW2T[DD * DD];   // sW2T[k*48+c] = w2[c][k]
    __shared__ float sW1[3 * DD];
    __shared__ float sB1[DD], sB2[DD], sW3[DD];
    int tid = threadIdx.x;
    for (int e = tid; e < DD * DD; e += 256) {
        int c = e / DD, k = e - c * DD;
        sW2T[k * DD + c] = f_w2[e];
    }
    if (tid < 3 * DD) sW1[tid] = f_w1[tid];
    if (tid < DD) { sB1[tid] = f_b1[tid]; sB2[tid] = f_b2[tid]; sW3[tid] = f_w3[tid]; }
    __syncthreads();

    int e = blockIdx.x * 256 + tid;        // 0 .. ND*NM*NM-1 (=32768, 128 blocks)
    int mj = e & (NM - 1);
    int mi = (e >> 4) & (NM - 1);
    int di = e >> 8;
    float dist = D_LO + di * DSTEP;
    float vmi = M_LO + mi * MSTEP;
    float vmj = M_LO + mj * MSTEP;

    float h1[DD];
    #pragma unroll
    for (int k = 0; k < DD; ++k) {
        float t = sB1[k] + dist * sW1[k] + vmi * sW1[DD + k] + vmj * sW1[2 * DD + k];
        h1[k] = gelu_exact(t);
    }
    float fm = f_b3[0];
    #pragma unroll 4
    for (int k = 0; k < DD; ++k) {       // partial unroll ok: only LDS arrays k-indexed
        float t = sB2[k];
        #pragma unroll
        for (int c = 0; c < DD; ++c) t += h1[c] * sW2T[k * DD + c];
        fm += gelu_exact(t) * sW3[k];
    }
    table[e] = fm;
}

// ---------------- pairwise force via table lookup ----------------
__global__ __launch_bounds__(256) void force_kernel(
    const float* __restrict__ pos, const float* __restrict__ mass,
    const float* __restrict__ table, float* __restrict__ force_acc) {
    __shared__ float sPi[BI * PSTR];
    __shared__ float sPj[BJ * PSTR];
    __shared__ float sMi[BI], sMj[BJ];
    __shared__ float sRat[BI][BJ + 1];

    const int tpb = NN / BI;              // 64
    const int TP = tpb * (tpb + 1) / 2;   // 2080
    int bid = blockIdx.x;
    int b = bid / TP;
    int tp = bid - b * TP;
    int it = (int)((sqrtf(8.0f * (float)tp + 1.0f) - 1.0f) * 0.5f);
    while ((it + 1) * (it + 2) / 2 <= tp) ++it;
    while (it * (it + 1) / 2 > tp) --it;
    int jt = tp - it * (it + 1) / 2;

    int i0 = it * BI, j0 = jt * BJ;
    int tid = threadIdx.x;

    for (int e = tid; e < BI * DD; e += 256) {
        int r = e / DD, d = e - r * DD;
        sPi[r * PSTR + d] = pos[(b * NN + i0 + r) * DD + d];
        sPj[r * PSTR + d] = pos[(b * NN + j0 + r) * DD + d];
    }
    if (tid < BI) sMi[tid] = mass[b * NN + i0 + tid];
    else if (tid < BI + BJ) sMj[tid - BI] = mass[b * NN + j0 + (tid - BI)];
    __syncthreads();

    // ---- Phase A: one thread per (i,j) pair: dist + trilinear lookup ----
    int ti = tid >> 4, tj = tid & 15;
    int gi = i0 + ti, gj = j0 + tj;
    const float* pi = &sPi[ti * PSTR];
    const float* pj = &sPj[tj * PSTR];

    float s2 = 0.0f;
    #pragma unroll
    for (int d = 0; d < DD; ++d) { float df = pi[d] - pj[d]; s2 += df * df; }
    float dist = fmaxf(sqrtf(s2), 0.01f);

    float td = fminf(fmaxf((dist - D_LO) * DINV, 0.0f), (float)(ND - 1) - 1e-3f);
    float tm = fminf(fmaxf((sMi[ti] - M_LO) * MINV, 0.0f), (float)(NM - 1) - 1e-3f);
    float tn = fminf(fmaxf((sMj[tj] - M_LO) * MINV, 0.0f), (float)(NM - 1) - 1e-3f);
    int di0 = (int)td; float fd = td - di0;
    int mi0 = (int)tm; float fi = tm - mi0;
    int nj0 = (int)tn; float fj = tn - nj0;

    const float* t0 = table + ((di0 * NM + mi0) * NM + nj0);
    float c000 = t0[0],            c001 = t0[1];
    float c010 = t0[NM],           c011 = t0[NM + 1];
    float c100 = t0[NM * NM],      c101 = t0[NM * NM + 1];
    float c110 = t0[NM * NM + NM], c111 = t0[NM * NM + NM + 1];
    float x00 = c000 + fj * (c001 - c000);
    float x01 = c010 + fj * (c011 - c010);
    float x10 = c100 + fj * (c101 - c100);
    float x11 = c110 + fj * (c111 - c110);
    float y0 = x00 + fi * (x01 - x00);
    float y1 = x10 + fi * (x11 - x10);
    float fmv = y0 + fd * (y1 - y0);

    float ratio = (gj <= gi) ? (fmv / dist) : 0.0f;  // j==i: disp=0 -> contributes 0
    sRat[ti][tj] = ratio;
    __syncthreads();

    // ---- Phase B: thread=(i, d-group of 3) accumulates over j ----
    int ti2 = tid >> 4, dg = tid & 15;
    int d0 = dg * 3;
    const float* pi2 = &sPi[ti2 * PSTR];
    float f0 = 0.0f, f1 = 0.0f, f2 = 0.0f;
    #pragma unroll
    for (int t = 0; t < BJ; ++t) {
        float r = sRat[ti2][t];
        const float* pj2 = &sPj[t * PSTR];
        f0 += r * (pi2[d0 + 0] - pj2[d0 + 0]);
        f1 += r * (pi2[d0 + 1] - pj2[d0 + 1]);
        f2 += r * (pi2[d0 + 2] - pj2[d0 + 2]);
    }
    float* fdst = force_acc + ((size_t)(b * NN + i0 + ti2) * DD + d0);
    atomicAdd(fdst + 0, f0);
    atomicAdd(fdst + 1, f1);
    atomicAdd(fdst + 2, f2);
}

// ---------------- integrate ----------------
__global__ void integrate_kernel(const float* __restrict__ pos, const float* __restrict__ vel,
                                 const float* __restrict__ force, const float* __restrict__ mass,
                                 const float* __restrict__ damping_p, const float* __restrict__ dt_p,
                                 float* __restrict__ out) {
    int e = blockIdx.x * blockDim.x + threadIdx.x;
    if (e >= BB * NN * DD) return;
    int p = e / DD;
    float damping = damping_p[0], dt = dt_p[0];
    float acc = force[e] / (mass[p] + 0.1f);
    float nv = damping * vel[e] + dt * acc;
    float np = pos[e] + dt * nv;
    out[e] = np;
    out[BB * NN * DD + e] = nv;
}

extern "C" void kernel_launch(void* const* d_in, const int* in_sizes, int n_in,
                              void* d_out, int out_size, void* d_ws, size_t ws_size,
                              hipStream_t stream) {
    const float* pos  = (const float*)d_in[0];
    const float* vel  = (const float*)d_in[1];
    const float* m_w1 = (const float*)d_in[2];
    const float* m_b1 = (const float*)d_in[3];
    const float* m_w2 = (const float*)d_in[4];
    const float* m_b2 = (const float*)d_in[5];
    const float* f_w1 = (const float*)d_in[6];
    const float* f_b1 = (const float*)d_in[7];
    const float* f_w2 = (const float*)d_in[8];
    const float* f_b2 = (const float*)d_in[9];
    const float* f_w3 = (const float*)d_in[10];
    const float* f_b3 = (const float*)d_in[11];
    const float* damping = (const float*)d_in[12];
    const float* dt   = (const float*)d_in[13];

    float* force_ws = (float*)d_ws;                    // BB*NN*DD floats
    float* mass_ws  = force_ws + BB * NN * DD;         // BB*NN floats
    float* table_ws = mass_ws + BB * NN;               // ND*NM*NM floats

    mass_kernel<<<(BB * NN + 255) / 256, 256, 0, stream>>>(pos, m_w1, m_b1, m_w2, m_b2,
                                                           mass_ws, force_ws);
    table_kernel<<<(ND * NM * NM) / 256, 256, 0, stream>>>(f_w1, f_b1, f_w2, f_b2, f_w3, f_b3,
                                                           table_ws);

    const int tpb = NN / BI;
    const int TP = tpb * (tpb + 1) / 2;
    force_kernel<<<BB * TP, 256, 0, stream>>>(pos, mass_ws, table_ws, force_ws);

    integrate_kernel<<<(BB * NN * DD + 255) / 256, 256, 0, stream>>>(
        pos, vel, force_ws, mass_ws, damping, dt, (float*)d_out);
}

// Round 5
// 61.373 us; speedup vs baseline: 3.1546x; 1.2510x over previous
//
#include <hip/hip_runtime.h>
#include <math.h>

#define BB 2
#define NN 1024
#define DD 48
#define DH 12
#define PSTR 52   // 208B row stride: 16B-aligned, 2-way bank alias on A-reads (free)

// force_mag(dist, mi, mj) lookup table, float2-paired along mj
#define ND 128
#define NM 16
#define D_LO 1.0f
#define D_HI 20.0f
#define DSTEP ((D_HI - D_LO) / (float)(ND - 1))
#define DINV  ((float)(ND - 1) / (D_HI - D_LO))
#define MSTEP (2.0f / (float)(NM - 1))
#define MINV  ((float)(NM - 1) / 2.0f)

__device__ __forceinline__ float gelu_exact(float x) {
    return 0.5f * x * (1.0f + erff(x * 0.70710678118654752f));
}
__device__ __forceinline__ float gelu_fast(float x) {
    float u = x * x;
    float p = __builtin_fmaf(0.044715f * x, u, x);
    float z = 1.5957691216057308f * p;
    float e = __expf(-z);
    return x * __builtin_amdgcn_rcpf(1.0f + e);
}
__device__ __forceinline__ float softplus_f(float x) {
    return (x > 20.0f) ? x : log1pf(expf(x));
}

// ======== prep: blocks [0,256) build table2; blocks [256,272) mass+norm+zero ========
__global__ __launch_bounds__(128) void prep_kernel(
    const float* __restrict__ pos,
    const float* __restrict__ m_w1, const float* __restrict__ m_b1,
    const float* __restrict__ m_w2, const float* __restrict__ m_b2,
    const float* __restrict__ f_w1, const float* __restrict__ f_b1,
    const float* __restrict__ f_w2, const float* __restrict__ f_b2,
    const float* __restrict__ f_w3, const float* __restrict__ f_b3,
    float* __restrict__ mass_out, float* __restrict__ normn,
    float* __restrict__ force_acc, float2* __restrict__ table2)
{
    int tid = threadIdx.x;
    if (blockIdx.x < 256) {
        __shared__ float sFm[128];
        int e = blockIdx.x * 128 + tid;            // 0..32767
        int mj = e & (NM - 1);
        int mi = (e >> 4) & (NM - 1);
        int di = e >> 8;
        float dist = D_LO + di * DSTEP;
        float vmi = mi * MSTEP, vmj = mj * MSTEP;
        float h1[DD];
        #pragma unroll
        for (int k = 0; k < DD; ++k) {
            float t = f_b1[k] + dist * f_w1[k] + vmi * f_w1[DD + k] + vmj * f_w1[2 * DD + k];
            h1[k] = gelu_fast(t);
        }
        float fm = f_b3[0];
        for (int k = 0; k < DD; ++k) {             // rolled: uniform scalar weight loads
            float t = f_b2[k];
            #pragma unroll
            for (int c = 0; c < DD; ++c) t += h1[c] * f_w2[c * DD + k];
            fm += gelu_fast(t) * f_w3[k];
        }
        sFm[tid] = fm;
        __syncthreads();
        float nbv = ((tid & 15) == 15) ? fm : sFm[tid + 1];  // mj+1 neighbor (mj=15 never deref'd)
        table2[e] = make_float2(fm, nbv);
    } else {
        int p = (blockIdx.x - 256) * 128 + tid;    // 0..2047
        float4* fr = (float4*)(force_acc + (size_t)p * DD);
        float4 z4 = make_float4(0.f, 0.f, 0.f, 0.f);
        #pragma unroll
        for (int k = 0; k < 12; ++k) fr[k] = z4;   // replay-safe zeroing

        const float4* pp = (const float4*)(pos + (size_t)p * DD);
        float x[DD]; float n2 = 0.f;
        #pragma unroll
        for (int k = 0; k < 12; ++k) {
            float4 v = pp[k];
            x[4*k+0] = v.x; x[4*k+1] = v.y; x[4*k+2] = v.z; x[4*k+3] = v.w;
            n2 += v.x*v.x + v.y*v.y + v.z*v.z + v.w*v.w;
        }
        float m2 = m_b2[0];
        #pragma unroll
        for (int k = 0; k < DH; ++k) {
            float h = m_b1[k];
            #pragma unroll
            for (int d = 0; d < DD; ++d) h += x[d] * m_w1[d * DH + k];
            m2 += gelu_exact(h) * m_w2[k];
        }
        mass_out[p] = softplus_f(m2);
        normn[p] = n2;
    }
}

// ======== force: block = (batch, 32-row i-strip, split s); 2 pos rows in regs/thread ========
__global__ __launch_bounds__(256) void force_kernel(
    const float* __restrict__ pos, const float* __restrict__ mass,
    const float* __restrict__ normn, const float2* __restrict__ table2,
    float* __restrict__ force_acc)
{
    __shared__ float sPj[2][16 * PSTR];
    __shared__ float sNj[2][16];
    __shared__ float sTn[2][16];
    __shared__ float sRatA[16][17];
    __shared__ float sRatB[16][17];

    // heavy<->light pairing: CU sees one low-strip and one high-strip block
    int z = blockIdx.x;                      // grid = 512
    int w = (z < 256) ? z : (767 - z);
    int b = w & 1;
    int r = w >> 1;                          // 0..255
    int s = r & 7;
    int strip = r >> 3;                      // 0..31
    int i0 = strip * 32;
    int tid = threadIdx.x;
    int ti = tid >> 4, tj = tid & 15;
    int u = (tid >> 2) & 3, q = tid & 3;
    int iA = i0 + ti, iB = i0 + 16 + ti;

    const float* prA = pos + (size_t)(b * NN + iA) * DD;
    const float* prB = pos + (size_t)(b * NN + iB) * DD;
    float piA[DD], piB[DD];
    #pragma unroll
    for (int k = 0; k < 12; ++k) {
        float4 va = ((const float4*)prA)[k];
        float4 vb = ((const float4*)prB)[k];
        piA[4*k+0] = va.x; piA[4*k+1] = va.y; piA[4*k+2] = va.z; piA[4*k+3] = va.w;
        piB[4*k+0] = vb.x; piB[4*k+1] = vb.y; piB[4*k+2] = vb.z; piB[4*k+3] = vb.w;
    }
    float nA = normn[b * NN + iA], nB = normn[b * NN + iB];
    float tmA = fminf(fmaxf(mass[b * NN + iA] * MINV, 0.f), (float)(NM - 1) - 1e-3f);
    float tmB = fminf(fmaxf(mass[b * NN + iB] * MINV, 0.f), (float)(NM - 1) - 1e-3f);
    int miA = (int)tmA; float fiA = tmA - miA; int miA16 = miA * NM;
    int miB = (int)tmB; float fiB = tmB - miB; int miB16 = miB * NM;

    float SA = 0.f, SB = 0.f;
    float VA[12], VB[12];
    #pragma unroll
    for (int c = 0; c < 12; ++c) { VA[c] = 0.f; VB[c] = 0.f; }

    int jtmax = 2 * strip + 1;
    int cur = 0;
    for (int jt = s; jt <= jtmax; jt += 8) {
        int j0 = jt * 16;
        // ---- stage j-tile into buf[cur] ----
        {
            const float* src = pos + (size_t)(b * NN + j0) * DD;
            #pragma unroll
            for (int k = 0; k < 3; ++k) {
                int e = tid + k * 256;
                int row = e / DD, col = e - row * DD;
                sPj[cur][row * PSTR + col] = src[e];
            }
            if (tid < 16) {
                sNj[cur][tid] = normn[b * NN + j0 + tid];
                float mjv = mass[b * NN + j0 + tid];
                sTn[cur][tid] = fminf(fmaxf(mjv * MINV, 0.f), (float)(NM - 1) - 1e-3f);
            }
        }
        __syncthreads();
        // ---- Phase A: dist via norm trick + table lookup, 2 rows/thread ----
        {
            const float4* pj4 = (const float4*)&sPj[cur][tj * PSTR];
            float dA = 0.f, dB = 0.f;
            #pragma unroll
            for (int k = 0; k < 12; ++k) {
                float4 v = pj4[k];
                dA = fmaf(piA[4*k+0], v.x, dA); dA = fmaf(piA[4*k+1], v.y, dA);
                dA = fmaf(piA[4*k+2], v.z, dA); dA = fmaf(piA[4*k+3], v.w, dA);
                dB = fmaf(piB[4*k+0], v.x, dB); dB = fmaf(piB[4*k+1], v.y, dB);
                dB = fmaf(piB[4*k+2], v.z, dB); dB = fmaf(piB[4*k+3], v.w, dB);
            }
            float njv = sNj[cur][tj];
            float tnv = sTn[cur][tj];
            int nj0 = (int)tnv; float fj = tnv - nj0;
            int gj = j0 + tj;

            // row A
            {
                float s2 = fmaxf(nA + njv - 2.f * dA, 0.f);
                float dist = fmaxf(sqrtf(s2), 0.01f);
                float td = fminf(fmaxf((dist - D_LO) * DINV, 0.f), (float)(ND - 1) - 1e-3f);
                int di0 = (int)td; float fd = td - di0;
                int idx = di0 * (NM * NM) + miA16 + nj0;
                float2 c00 = table2[idx],            c01 = table2[idx + NM];
                float2 c10 = table2[idx + NM * NM],  c11 = table2[idx + NM * NM + NM];
                float x00 = c00.x + fj * (c00.y - c00.x);
                float x01 = c01.x + fj * (c01.y - c01.x);
                float x10 = c10.x + fj * (c10.y - c10.x);
                float x11 = c11.x + fj * (c11.y - c11.x);
                float y0 = x00 + fiA * (x01 - x00);
                float y1 = x10 + fiA * (x11 - x10);
                float fmv = y0 + fd * (y1 - y0);
                sRatA[ti][tj] = (gj <= iA) ? fmv * __builtin_amdgcn_rcpf(dist) : 0.f;
            }
            // row B
            {
                float s2 = fmaxf(nB + njv - 2.f * dB, 0.f);
                float dist = fmaxf(sqrtf(s2), 0.01f);
                float td = fminf(fmaxf((dist - D_LO) * DINV, 0.f), (float)(ND - 1) - 1e-3f);
                int di0 = (int)td; float fd = td - di0;
                int idx = di0 * (NM * NM) + miB16 + nj0;
                float2 c00 = table2[idx],            c01 = table2[idx + NM];
                float2 c10 = table2[idx + NM * NM],  c11 = table2[idx + NM * NM + NM];
                float x00 = c00.x + fj * (c00.y - c00.x);
                float x01 = c01.x + fj * (c01.y - c01.x);
                float x10 = c10.x + fj * (c10.y - c10.x);
                float x11 = c11.x + fj * (c11.y - c11.x);
                float y0 = x00 + fiB * (x01 - x00);
                float y1 = x10 + fiB * (x11 - x10);
                float fmv = y0 + fd * (y1 - y0);
                sRatB[ti][tj] = (gj <= iB) ? fmv * __builtin_amdgcn_rcpf(dist) : 0.f;
            }
        }
        __syncthreads();
        // ---- Phase B: V += r*pj, S += r  (thread = (ti, u over t, q over 12-dim slice)) ----
        {
            #pragma unroll
            for (int k = 0; k < 4; ++k) {
                int t = 4 * k + u;
                float rA = sRatA[ti][t];
                float rB = sRatB[ti][t];
                SA += rA; SB += rB;
                const float4* pr = (const float4*)&sPj[cur][t * PSTR + 12 * q];
                #pragma unroll
                for (int c = 0; c < 3; ++c) {
                    float4 v = pr[c];
                    VA[4*c+0] = fmaf(rA, v.x, VA[4*c+0]);
                    VA[4*c+1] = fmaf(rA, v.y, VA[4*c+1]);
                    VA[4*c+2] = fmaf(rA, v.z, VA[4*c+2]);
                    VA[4*c+3] = fmaf(rA, v.w, VA[4*c+3]);
                    VB[4*c+0] = fmaf(rB, v.x, VB[4*c+0]);
                    VB[4*c+1] = fmaf(rB, v.y, VB[4*c+1]);
                    VB[4*c+2] = fmaf(rB, v.z, VB[4*c+2]);
                    VB[4*c+3] = fmaf(rB, v.w, VB[4*c+3]);
                }
            }
        }
        cur ^= 1;
    }

    // ---- reduce partial (over u) and write: f_d = pi_d*S - V_d ----
    #pragma unroll
    for (int off = 4; off <= 8; off <<= 1) {
        SA += __shfl_xor(SA, off); SB += __shfl_xor(SB, off);
        #pragma unroll
        for (int c = 0; c < 12; ++c) {
            VA[c] += __shfl_xor(VA[c], off);
            VB[c] += __shfl_xor(VB[c], off);
        }
    }
    if (u == 0) {
        int d0 = 12 * q;
        float* fA = force_acc + (size_t)(b * NN + iA) * DD + d0;
        float* fB = force_acc + (size_t)(b * NN + iB) * DD + d0;
        const float* pA = prA + d0;
        const float* pB = prB + d0;
        #pragma unroll
        for (int c = 0; c < 12; ++c) {
            atomicAdd(&fA[c], pA[c] * SA - VA[c]);
            atomicAdd(&fB[c], pB[c] * SB - VB[c]);
        }
    }
}

// ======== integrate (float4) ========
__global__ void integrate_kernel(const float* __restrict__ pos, const float* __restrict__ vel,
                                 const float* __restrict__ force, const float* __restrict__ mass,
                                 const float* __restrict__ damping_p, const float* __restrict__ dt_p,
                                 float* __restrict__ out) {
    int e4 = blockIdx.x * blockDim.x + threadIdx.x;
    const int N4 = BB * NN * DD / 4;
    if (e4 >= N4) return;
    int p = (e4 * 4) / DD;
    float damping = damping_p[0], dt = dt_p[0];
    float inv = 1.0f / (mass[p] + 0.1f);
    float4 f = ((const float4*)force)[e4];
    float4 v = ((const float4*)vel)[e4];
    float4 x = ((const float4*)pos)[e4];
    float4 nv, np;
    nv.x = damping * v.x + dt * (f.x * inv);
    nv.y = damping * v.y + dt * (f.y * inv);
    nv.z = damping * v.z + dt * (f.z * inv);
    nv.w = damping * v.w + dt * (f.w * inv);
    np.x = x.x + dt * nv.x; np.y = x.y + dt * nv.y;
    np.z = x.z + dt * nv.z; np.w = x.w + dt * nv.w;
    ((float4*)out)[e4] = np;
    ((float4*)out)[N4 + e4] = nv;
}

extern "C" void kernel_launch(void* const* d_in, const int* in_sizes, int n_in,
                              void* d_out, int out_size, void* d_ws, size_t ws_size,
                              hipStream_t stream) {
    const float* pos  = (const float*)d_in[0];
    const float* vel  = (const float*)d_in[1];
    const float* m_w1 = (const float*)d_in[2];
    const float* m_b1 = (const float*)d_in[3];
    const float* m_w2 = (const float*)d_in[4];
    const float* m_b2 = (const float*)d_in[5];
    const float* f_w1 = (const float*)d_in[6];
    const float* f_b1 = (const float*)d_in[7];
    const float* f_w2 = (const float*)d_in[8];
    const float* f_b2 = (const float*)d_in[9];
    const float* f_w3 = (const float*)d_in[10];
    const float* f_b3 = (const float*)d_in[11];
    const float* damping = (const float*)d_in[12];
    const float* dt   = (const float*)d_in[13];

    float* force_ws = (float*)d_ws;                    // 98304 floats
    float* mass_ws  = force_ws + BB * NN * DD;         // 2048
    float* norm_ws  = mass_ws + BB * NN;               // 2048
    float2* table2_ws = (float2*)(norm_ws + BB * NN);  // 32768 float2

    prep_kernel<<<272, 128, 0, stream>>>(pos, m_w1, m_b1, m_w2, m_b2,
                                         f_w1, f_b1, f_w2, f_b2, f_w3, f_b3,
                                         mass_ws, norm_ws, force_ws, table2_ws);

    force_kernel<<<512, 256, 0, stream>>>(pos, mass_ws, norm_ws, table2_ws, force_ws);

    integrate_kernel<<<(BB * NN * DD / 4 + 255) / 256, 256, 0, stream>>>(
        pos, vel, force_ws, mass_ws, damping, dt, (float*)d_out);
}